// Round 7
// baseline (529.017 us; speedup 1.0000x reference)
//
#include <hip/hip_runtime.h>

// SNN layer on MI355X. i[t,b,o] = sum_k x[b,k,t]*w[k,o]; per-(b,o) sequential
// LIF scan over t; spikes (0/1) fp32 [B,O,T].
//
// Precision: spike decision v>=1.0 needs i to ~2e-3 absolute (|i|~1.8e5);
// resets every ~2.5 steps stop error accumulation. fp32 GEMM: ~0.2 error (too
// big). fp64 GEMM: exact but capped at 214us (78.6 TF). This version: exact
// fixed-point via i8 MFMA (Ozaki-style): X=rint(x*2^28) -> 4 signed i8 limbs
// (exact split), W=rint(w*2^15) likewise; 13 limb-pair GEMMs (weight p+q>=2)
// in exact i32 accumulation (mfma_i32_16x16x64_i8, 3944 TOPS); combine in
// fp64. eps_i ~ 2.8e-4 -> expected spike flips ~0.01. Dropped pairs (p+q<2)
// contribute ~5e-6. Same-weight pairs share accumulators (max |sum| < 3.4e7).
//
//   prep_x: x[b,k,t] f32 -> XT[b][p][k/16][t(512,zero-pad)][16] i8  (67 MB ws)
//   prep_w: w[k,o]   f32 -> WT[p][k/16][o][16] i8                   (1 MB ws)
//   snn_i8: fused GEMM(i8 MFMA)+scan; i-chunk in LDS; v persistent.
// Fallback (ws too small): proven round-4 fp64 fused kernel.

#define NB 64
#define NI 512
#define NO 512
#define NT 500

typedef int v4i __attribute__((ext_vector_type(4)));
typedef double d2 __attribute__((ext_vector_type(2)));

#define XT_B_STRIDE 1048576   // bytes per batch in XT
#define P_STRIDE    262144    // bytes per limb plane
#define KB_STRIDE   8192      // bytes per k-block (512 rows * 16B)
#define XT_BYTES    67108864
#define WT_BYTES    1048576

// ===================== prep_x: transpose + limb-slice =====================
__global__ __launch_bounds__(256)
void prep_x(const float* __restrict__ xg, unsigned char* __restrict__ xt) {
    __shared__ float xs[64][65];
    const int tid = threadIdx.x;
    const int b   = blockIdx.x >> 3;
    const int kc  = (blockIdx.x & 7) * 64;
    const int sk  = tid >> 2;           // staged k-row 0..63
    const int st  = (tid & 3) * 16;     // staged t-offset
    const int ct  = tid & 63;           // compute t
    const int ckb = tid >> 6;           // compute k-block 0..3

    for (int tc = 0; tc < 512; tc += 64) {
        __syncthreads();
        const float* px = xg + ((size_t)(b * NI + kc + sk)) * NT + tc + st;
        #pragma unroll
        for (int e = 0; e < 16; ++e)
            xs[sk][st + e] = (tc + st + e < NT) ? px[e] : 0.0f;   // zero-pad t
        __syncthreads();

        unsigned int u0[4] = {0,0,0,0}, u1[4] = {0,0,0,0};
        unsigned int u2[4] = {0,0,0,0}, u3[4] = {0,0,0,0};
        #pragma unroll
        for (int e = 0; e < 16; ++e) {
            const float xv = xs[ckb * 16 + e][ct];
            int X = __float2int_rn(xv * 268435456.0f);        // x * 2^28 (exact scale)
            const int a0 = (X << 24) >> 24; X = (X - a0) >> 8;
            const int a1 = (X << 24) >> 24; X = (X - a1) >> 8;
            const int a2 = (X << 24) >> 24; const int a3 = (X - a2) >> 8;
            const int sh = (e & 3) * 8; const int d = e >> 2;
            u0[d] |= (unsigned)(a0 & 0xFF) << sh;
            u1[d] |= (unsigned)(a1 & 0xFF) << sh;
            u2[d] |= (unsigned)(a2 & 0xFF) << sh;
            u3[d] |= (unsigned)(a3 & 0xFF) << sh;
        }
        unsigned char* base = xt + (size_t)b * XT_B_STRIDE
                              + (size_t)(kc / 16 + ckb) * KB_STRIDE
                              + (size_t)(tc + ct) * 16;
        *(uint4*)(base)                = make_uint4(u0[0], u0[1], u0[2], u0[3]);
        *(uint4*)(base + P_STRIDE)     = make_uint4(u1[0], u1[1], u1[2], u1[3]);
        *(uint4*)(base + 2 * P_STRIDE) = make_uint4(u2[0], u2[1], u2[2], u2[3]);
        *(uint4*)(base + 3 * P_STRIDE) = make_uint4(u3[0], u3[1], u3[2], u3[3]);
    }
}

// ===================== prep_w =====================
__global__ __launch_bounds__(256)
void prep_w(const float* __restrict__ wg, unsigned char* __restrict__ wtb) {
    __shared__ float wsx[64][65];
    const int tid = threadIdx.x;
    const int kc  = blockIdx.x * 64;
    const int sk  = tid >> 2;
    const int so  = (tid & 3) * 16;
    const int co  = tid & 63;
    const int ckb = tid >> 6;

    for (int oc = 0; oc < 512; oc += 64) {
        __syncthreads();
        const float* pw = wg + (size_t)(kc + sk) * NO + oc + so;
        #pragma unroll
        for (int e = 0; e < 16; e += 4) {
            float4 f = *(const float4*)(pw + e);
            wsx[sk][so + e + 0] = f.x; wsx[sk][so + e + 1] = f.y;
            wsx[sk][so + e + 2] = f.z; wsx[sk][so + e + 3] = f.w;
        }
        __syncthreads();

        unsigned int u0[4] = {0,0,0,0}, u1[4] = {0,0,0,0};
        unsigned int u2[4] = {0,0,0,0}, u3[4] = {0,0,0,0};
        #pragma unroll
        for (int e = 0; e < 16; ++e) {
            const float wv = wsx[ckb * 16 + e][co];
            int X = __float2int_rn(wv * 32768.0f);            // w * 2^15
            const int a0 = (X << 24) >> 24; X = (X - a0) >> 8;
            const int a1 = (X << 24) >> 24; X = (X - a1) >> 8;
            const int a2 = (X << 24) >> 24; const int a3 = (X - a2) >> 8;
            const int sh = (e & 3) * 8; const int d = e >> 2;
            u0[d] |= (unsigned)(a0 & 0xFF) << sh;
            u1[d] |= (unsigned)(a1 & 0xFF) << sh;
            u2[d] |= (unsigned)(a2 & 0xFF) << sh;
            u3[d] |= (unsigned)(a3 & 0xFF) << sh;
        }
        unsigned char* base = wtb + (size_t)(kc / 16 + ckb) * KB_STRIDE
                              + (size_t)(oc + co) * 16;
        *(uint4*)(base)                = make_uint4(u0[0], u0[1], u0[2], u0[3]);
        *(uint4*)(base + P_STRIDE)     = make_uint4(u1[0], u1[1], u1[2], u1[3]);
        *(uint4*)(base + 2 * P_STRIDE) = make_uint4(u2[0], u2[1], u2[2], u2[3]);
        *(uint4*)(base + 3 * P_STRIDE) = make_uint4(u3[0], u3[1], u3[2], u3[3]);
    }
}

// ===================== main: i8-MFMA GEMM + fused scan =====================
#define MFMA_I8(a, b, c) __builtin_amdgcn_mfma_i32_16x16x64_i8(a, b, c, 0, 0, 0)

__global__ __launch_bounds__(256, 2)
void snn_i8(const unsigned char* __restrict__ xt, const unsigned char* __restrict__ wtb,
            float* __restrict__ yg) {
    // A: 8 KB  [p][kb][32t][16]; B: 16 KB [p][kb][64o][16]; ib aliases (16.9 KB)
    __shared__ __align__(16) double smem_d[3072];              // 24576 B
    unsigned char* A_lds = (unsigned char*)smem_d;
    unsigned char* B_lds = (unsigned char*)smem_d + 8192;
    double (*ib)[66] = (double(*)[66])smem_d;

    const int tid  = threadIdx.x;
    const int lane = tid & 63;
    const int wv   = tid >> 6;
    const int wt_  = wv & 1;        // t-half (16 rows)
    const int wo   = wv >> 1;       // o-half (32 cols)
    const int lr   = lane & 15;
    const int lg   = lane >> 4;

    // XCD swizzle (proven round-4): 8 o-tiles of one batch share an XCD.
    const int L  = blockIdx.x;
    const int b  = (L & 7) + ((L >> 6) << 3);
    const int o0 = ((L >> 3) & 7) * 64;

    const unsigned char* xb = xt + (size_t)b * XT_B_STRIDE;
    const unsigned char* wb = wtb + (size_t)o0 * 16;

    const double alpha = 0.001 / 50.0;
    double v = 0.0;

    v4i acc[5][2];
    #pragma unroll
    for (int s = 0; s < 5; ++s) { acc[s][0] = (v4i){0,0,0,0}; acc[s][1] = (v4i){0,0,0,0}; }

    uint4 ra[2], rb[4];
    auto prefetch = [&](int step) {
        const int tcs  = step >> 3;
        const int kc16 = (step & 7) * 4;
        {
            int c = tid, p = c >> 7, kb = (c >> 5) & 3, t = c & 31;
            ra[0] = *(const uint4*)(xb + (size_t)p * P_STRIDE
                     + (size_t)(kc16 + kb) * KB_STRIDE + (size_t)(tcs * 32 + t) * 16);
            c = tid + 256; p = c >> 7; kb = (c >> 5) & 3; t = c & 31;
            ra[1] = *(const uint4*)(xb + (size_t)p * P_STRIDE
                     + (size_t)(kc16 + kb) * KB_STRIDE + (size_t)(tcs * 32 + t) * 16);
        }
        #pragma unroll
        for (int j = 0; j < 4; ++j) {
            const int c = tid + j * 256, p = c >> 8, kb = (c >> 6) & 3, o = c & 63;
            rb[j] = *(const uint4*)(wb + (size_t)p * P_STRIDE
                     + (size_t)(kc16 + kb) * KB_STRIDE + (size_t)o * 16);
        }
    };

    prefetch(0);

    for (int step = 0; step < 128; ++step) {
        __syncthreads();                 // prior frag reads / scan complete
        *(uint4*)(A_lds + tid * 16)         = ra[0];
        *(uint4*)(A_lds + (tid + 256) * 16) = ra[1];
        #pragma unroll
        for (int j = 0; j < 4; ++j)
            *(uint4*)(B_lds + (tid + j * 256) * 16) = rb[j];
        __syncthreads();

        if (step + 1 < 128) prefetch(step + 1);   // HBM/L2 latency under MFMA

        v4i aF[4], bF[4][2];
        #pragma unroll
        for (int p = 0; p < 4; ++p)
            aF[p] = *(const v4i*)(A_lds + (((p * 4 + lg) * 32) + wt_ * 16 + lr) * 16);
        #pragma unroll
        for (int p = 0; p < 4; ++p)
            #pragma unroll
            for (int oc = 0; oc < 2; ++oc)
                bF[p][oc] = *(const v4i*)(B_lds + (((p * 4 + lg) * 64) + wo * 32 + oc * 16 + lr) * 16);

        #pragma unroll
        for (int oc = 0; oc < 2; ++oc) {
            acc[0][oc] = MFMA_I8(aF[0], bF[2][oc], acc[0][oc]);
            acc[0][oc] = MFMA_I8(aF[1], bF[1][oc], acc[0][oc]);
            acc[0][oc] = MFMA_I8(aF[2], bF[0][oc], acc[0][oc]);
            acc[1][oc] = MFMA_I8(aF[0], bF[3][oc], acc[1][oc]);
            acc[1][oc] = MFMA_I8(aF[1], bF[2][oc], acc[1][oc]);
            acc[1][oc] = MFMA_I8(aF[2], bF[1][oc], acc[1][oc]);
            acc[1][oc] = MFMA_I8(aF[3], bF[0][oc], acc[1][oc]);
            acc[2][oc] = MFMA_I8(aF[1], bF[3][oc], acc[2][oc]);
            acc[2][oc] = MFMA_I8(aF[2], bF[2][oc], acc[2][oc]);
            acc[2][oc] = MFMA_I8(aF[3], bF[1][oc], acc[2][oc]);
            acc[3][oc] = MFMA_I8(aF[2], bF[3][oc], acc[3][oc]);
            acc[3][oc] = MFMA_I8(aF[3], bF[2][oc], acc[3][oc]);
            acc[4][oc] = MFMA_I8(aF[3], bF[3][oc], acc[4][oc]);
        }

        if ((step & 7) == 7) {           // K done for this t-chunk
            const int tc = step >> 3;
            __syncthreads();             // all frag reads done; A/B becomes ib
            // D: col = lane&15 (o), row = 4*(lane>>4)+reg (t). Combine limbs:
            // i = sum_s ACC_s * 2^(8*(s+2) - 43)
            #pragma unroll
            for (int oc = 0; oc < 2; ++oc) {
                const int o_loc = wo * 32 + oc * 16 + lr;
                #pragma unroll
                for (int r = 0; r < 4; ++r) {
                    const double iv =
                          (double)acc[0][oc][r] * 0x1p-27
                        + (double)acc[1][oc][r] * 0x1p-19
                        + (double)acc[2][oc][r] * 0x1p-11
                        + (double)acc[3][oc][r] * 0x1p-3
                        + (double)acc[4][oc][r] * 0x1p+5;
                    ib[wt_ * 16 + lg * 4 + r][o_loc] = iv;
                }
            }
            #pragma unroll
            for (int s = 0; s < 5; ++s) { acc[s][0] = (v4i){0,0,0,0}; acc[s][1] = (v4i){0,0,0,0}; }
            __syncthreads();

            // sequential LIF scan, wave 0; t>=500 rows are exact zeros.
            if (tid < 64) {
                float fv[32];
                #pragma unroll
                for (int t = 0; t < 32; ++t) {
                    const double iv = ib[t][tid];
                    v += (iv - v) * alpha;
                    const bool s = (v >= 1.0);
                    fv[t] = s ? 1.0f : 0.0f;
                    if (s) v = 0.0;
                }
                const int tbase = tc * 32;
                float* py = yg + ((size_t)(b * NO) + o0 + tid) * NT + tbase;
                const int nv = (tbase + 32 <= NT) ? 32 : (NT - tbase);
                for (int q = 0; q * 4 < nv; ++q)
                    *(float4*)(py + q * 4) =
                        make_float4(fv[q*4], fv[q*4+1], fv[q*4+2], fv[q*4+3]);
            }
        }
    }
}

// ============ fallback: round-4 fused fp64 kernel (proven, ws-free) ============
#define OT 64
#define TT 64
#define KC 32
#define TP (TT + 2)
#define OP (OT + 2)

__global__ __launch_bounds__(256, 2)
void snn_v2(const float* __restrict__ xg, const float* __restrict__ wg,
            float* __restrict__ yg) {
    __shared__ double smem[KC * TP + KC * OP];
    double (*xs)[TP]  = (double(*)[TP])smem;
    double (*wsh)[OP] = (double(*)[OP])(smem + KC * TP);
    double (*ib)[OP]  = (double(*)[OP])smem;

    const int tid = threadIdx.x;
    const int p2  = (tid & 31) * 2;
    const int t0  = (tid >> 5) * 8;
    const int L   = blockIdx.x;
    const int b   = (L & 7) + ((L >> 6) << 3);
    const int o0  = ((L >> 3) & 7) * OT;
    const int sk  = tid >> 3;
    const int se  = (tid & 7) * 8;
    const double alpha = 0.001 / 50.0;
    double v = 0.0;

    for (int tc = 0; tc < NT; tc += TT) {
        const int tlim = (NT - tc < TT) ? (NT - tc) : TT;
        double a0[8], a1[8];
        #pragma unroll
        for (int j = 0; j < 8; ++j) { a0[j] = 0.0; a1[j] = 0.0; }

        for (int kc = 0; kc < NI; kc += KC) {
            __syncthreads();
            {
                const float* px = xg + ((size_t)(b * NI + kc + sk)) * NT + tc + se;
                double* dx = &xs[sk][se];
                if (tlim == TT) {
                    #pragma unroll
                    for (int e = 0; e < 2; ++e) {
                        float4 f = ((const float4*)px)[e];
                        d2 lo = {(double)f.x, (double)f.y};
                        d2 hi = {(double)f.z, (double)f.w};
                        *(d2*)(dx + e * 4) = lo; *(d2*)(dx + e * 4 + 2) = hi;
                    }
                } else {
                    #pragma unroll
                    for (int e = 0; e < 8; ++e) {
                        double val = 0.0;
                        if (se + e < tlim) val = (double)px[e];
                        dx[e] = val;
                    }
                }
            }
            {
                const float* pw = wg + (size_t)(kc + sk) * NO + o0 + se;
                double* dw = &wsh[sk][se];
                #pragma unroll
                for (int e = 0; e < 2; ++e) {
                    float4 f = ((const float4*)pw)[e];
                    d2 lo = {(double)f.x, (double)f.y};
                    d2 hi = {(double)f.z, (double)f.w};
                    *(d2*)(dw + e * 4) = lo; *(d2*)(dw + e * 4 + 2) = hi;
                }
            }
            __syncthreads();
            #pragma unroll 4
            for (int k = 0; k < KC; ++k) {
                const d2 w2 = *(const d2*)&wsh[k][p2];
                double x8[8];
                #pragma unroll
                for (int e = 0; e < 4; ++e)
                    *(d2*)&x8[e * 2] = *(const d2*)&xs[k][t0 + e * 2];
                #pragma unroll
                for (int j = 0; j < 8; ++j) {
                    a0[j] += x8[j] * w2[0];
                    a1[j] += x8[j] * w2[1];
                }
            }
        }
        __syncthreads();
        #pragma unroll
        for (int j = 0; j < 8; ++j) {
            d2 c = {a0[j], a1[j]};
            *(d2*)&ib[t0 + j][p2] = c;
        }
        __syncthreads();
        if (tid < 64) {
            float* py = yg + ((size_t)(b * NO + o0 + tid)) * NT + tc;
            for (int tb = 0; tb < TT; tb += 16) {
                double iv[16];
                #pragma unroll
                for (int u = 0; u < 16; ++u) iv[u] = ib[tb + u][tid];
                float fv[16];
                #pragma unroll
                for (int u = 0; u < 16; ++u) {
                    v += (iv[u] - v) * alpha;
                    const bool s = (v >= 1.0);
                    fv[u] = s ? 1.0f : 0.0f;
                    if (s) v = 0.0;
                }
                #pragma unroll
                for (int q = 0; q < 4; ++q)
                    if (tb + q * 4 < tlim)
                        *(float4*)(py + tb + q * 4) =
                            make_float4(fv[q*4], fv[q*4+1], fv[q*4+2], fv[q*4+3]);
            }
        }
    }
}

extern "C" void kernel_launch(void* const* d_in, const int* in_sizes, int n_in,
                              void* d_out, int out_size, void* d_ws, size_t ws_size,
                              hipStream_t stream) {
    const float* x = (const float*)d_in[0];   // [64, 512, 500]
    const float* w = (const float*)d_in[1];   // [512, 512]
    float* y = (float*)d_out;                 // [64, 512, 500]
    (void)in_sizes; (void)n_in; (void)out_size;

    const size_t need = (size_t)XT_BYTES + WT_BYTES;   // 68,157,440 B
    if (ws_size >= need) {
        unsigned char* xt  = (unsigned char*)d_ws;
        unsigned char* wtb = (unsigned char*)d_ws + XT_BYTES;
        prep_x<<<512, 256, 0, stream>>>(x, xt);
        prep_w<<<8, 256, 0, stream>>>(w, wtb);
        snn_i8<<<512, 256, 0, stream>>>(xt, wtb, y);
    } else {
        snn_v2<<<512, 256, 0, stream>>>(x, w, y);      // proven fallback
    }
}

// Round 8
// 268.184 us; speedup vs baseline: 1.9726x; 1.9726x over previous
//
#include <hip/hip_runtime.h>

// SNN layer on MI355X. i[t,b,o] = sum_k x[b,k,t]*w[k,o]; per-(b,o) sequential
// LIF scan over t; spikes (0/1) fp32 [B,O,T].
//
// Exact fixed-point i8-MFMA path (round-7 proven, absmax 0.0):
// X=rint(x*2^28) -> 4 signed i8 limbs, W=rint(w*2^15) -> 4 limbs; 13 limb
// pairs (p+q>=2) accumulated exactly in i32 (mfma_i32_16x16x64_i8), combined
// in fp64; eps_i ~ 2.8e-4 vs ~2e-3 budget.
//
// Round-7 post-mortem: fused kernel was latency-bound (MfmaUtil 9%, VALUBusy
// 5.6%, both pipes idle ~90%): 128 steps/block x 2 barriers + operand LDS
// round-trip, 2 blocks/CU. But XT/WT are ALREADY stored as per-lane MFMA
// fragments -> this version loads A/B register-direct from L2 (no operand
// LDS, no K-loop barriers), wave-tile 32t x 32o (52 MFMA / 16 loads), 2
// barriers per 64-t chunk. Scan distributed across all 4 waves (16 ch each).

#define NB 64
#define NI 512
#define NO 512
#define NT 500

typedef int v4i __attribute__((ext_vector_type(4)));
typedef double d2 __attribute__((ext_vector_type(2)));

#define XT_B_STRIDE 1048576   // bytes per batch in XT
#define P_STRIDE    262144    // bytes per limb plane
#define KB_STRIDE   8192      // bytes per k-block (512 rows * 16B)
#define XT_BYTES    67108864
#define WT_BYTES    1048576

// ===================== prep_x: transpose + limb-slice (proven r7) ==========
__global__ __launch_bounds__(256)
void prep_x(const float* __restrict__ xg, unsigned char* __restrict__ xt) {
    __shared__ float xs[64][65];
    const int tid = threadIdx.x;
    const int b   = blockIdx.x >> 3;
    const int kc  = (blockIdx.x & 7) * 64;
    const int sk  = tid >> 2;
    const int st  = (tid & 3) * 16;
    const int ct  = tid & 63;
    const int ckb = tid >> 6;

    for (int tc = 0; tc < 512; tc += 64) {
        __syncthreads();
        const float* px = xg + ((size_t)(b * NI + kc + sk)) * NT + tc + st;
        #pragma unroll
        for (int e = 0; e < 16; ++e)
            xs[sk][st + e] = (tc + st + e < NT) ? px[e] : 0.0f;
        __syncthreads();

        unsigned int u0[4] = {0,0,0,0}, u1[4] = {0,0,0,0};
        unsigned int u2[4] = {0,0,0,0}, u3[4] = {0,0,0,0};
        #pragma unroll
        for (int e = 0; e < 16; ++e) {
            const float xv = xs[ckb * 16 + e][ct];
            int X = __float2int_rn(xv * 268435456.0f);
            const int a0 = (X << 24) >> 24; X = (X - a0) >> 8;
            const int a1 = (X << 24) >> 24; X = (X - a1) >> 8;
            const int a2 = (X << 24) >> 24; const int a3 = (X - a2) >> 8;
            const int sh = (e & 3) * 8; const int d = e >> 2;
            u0[d] |= (unsigned)(a0 & 0xFF) << sh;
            u1[d] |= (unsigned)(a1 & 0xFF) << sh;
            u2[d] |= (unsigned)(a2 & 0xFF) << sh;
            u3[d] |= (unsigned)(a3 & 0xFF) << sh;
        }
        unsigned char* base = xt + (size_t)b * XT_B_STRIDE
                              + (size_t)(kc / 16 + ckb) * KB_STRIDE
                              + (size_t)(tc + ct) * 16;
        *(uint4*)(base)                = make_uint4(u0[0], u0[1], u0[2], u0[3]);
        *(uint4*)(base + P_STRIDE)     = make_uint4(u1[0], u1[1], u1[2], u1[3]);
        *(uint4*)(base + 2 * P_STRIDE) = make_uint4(u2[0], u2[1], u2[2], u2[3]);
        *(uint4*)(base + 3 * P_STRIDE) = make_uint4(u3[0], u3[1], u3[2], u3[3]);
    }
}

// ===================== prep_w (proven r7) =====================
__global__ __launch_bounds__(256)
void prep_w(const float* __restrict__ wg, unsigned char* __restrict__ wtb) {
    __shared__ float wsx[64][65];
    const int tid = threadIdx.x;
    const int kc  = blockIdx.x * 64;
    const int sk  = tid >> 2;
    const int so  = (tid & 3) * 16;
    const int co  = tid & 63;
    const int ckb = tid >> 6;

    for (int oc = 0; oc < 512; oc += 64) {
        __syncthreads();
        const float* pw = wg + (size_t)(kc + sk) * NO + oc + so;
        #pragma unroll
        for (int e = 0; e < 16; e += 4) {
            float4 f = *(const float4*)(pw + e);
            wsx[sk][so + e + 0] = f.x; wsx[sk][so + e + 1] = f.y;
            wsx[sk][so + e + 2] = f.z; wsx[sk][so + e + 3] = f.w;
        }
        __syncthreads();

        unsigned int u0[4] = {0,0,0,0}, u1[4] = {0,0,0,0};
        unsigned int u2[4] = {0,0,0,0}, u3[4] = {0,0,0,0};
        #pragma unroll
        for (int e = 0; e < 16; ++e) {
            const float wv = wsx[ckb * 16 + e][co];
            int X = __float2int_rn(wv * 32768.0f);
            const int a0 = (X << 24) >> 24; X = (X - a0) >> 8;
            const int a1 = (X << 24) >> 24; X = (X - a1) >> 8;
            const int a2 = (X << 24) >> 24; const int a3 = (X - a2) >> 8;
            const int sh = (e & 3) * 8; const int d = e >> 2;
            u0[d] |= (unsigned)(a0 & 0xFF) << sh;
            u1[d] |= (unsigned)(a1 & 0xFF) << sh;
            u2[d] |= (unsigned)(a2 & 0xFF) << sh;
            u3[d] |= (unsigned)(a3 & 0xFF) << sh;
        }
        unsigned char* base = wtb + (size_t)(kc / 16 + ckb) * KB_STRIDE
                              + (size_t)(oc + co) * 16;
        *(uint4*)(base)                = make_uint4(u0[0], u0[1], u0[2], u0[3]);
        *(uint4*)(base + P_STRIDE)     = make_uint4(u1[0], u1[1], u1[2], u1[3]);
        *(uint4*)(base + 2 * P_STRIDE) = make_uint4(u2[0], u2[1], u2[2], u2[3]);
        *(uint4*)(base + 3 * P_STRIDE) = make_uint4(u3[0], u3[1], u3[2], u3[3]);
    }
}

// ============== main: register-direct i8-MFMA GEMM + fused scan ==============
#define MFMA_I8(a, b, c) __builtin_amdgcn_mfma_i32_16x16x64_i8(a, b, c, 0, 0, 0)

__global__ __launch_bounds__(256, 2)
void snn_i8v2(const unsigned char* __restrict__ xt,
              const unsigned char* __restrict__ wtb,
              float* __restrict__ yg) {
    __shared__ double ib[64][66];        // 33,792 B (i-values only)

    const int tid  = threadIdx.x;
    const int lane = tid & 63;
    const int wv   = tid >> 6;      // wave 0..3
    const int wt   = wv & 1;        // t-half (32 rows)
    const int wo   = wv >> 1;       // o-half (32 cols)
    const int lr   = lane & 15;
    const int lg   = lane >> 4;

    // XCD swizzle (proven): 8 o-tiles of one batch share an XCD.
    const int L  = blockIdx.x;
    const int b  = (L & 7) + ((L >> 6) << 3);
    const int o0 = ((L >> 3) & 7) * 64;

    const unsigned char* xb = xt + (size_t)b * XT_B_STRIDE;
    const unsigned char* wb = wtb + (size_t)o0 * 16;

    const double alpha = 0.001 / 50.0;
    double v = 0.0;                 // scan state (lanes<16 of each wave)

    for (int tc = 0; tc < 8; ++tc) {            // 8 chunks of 64 t (512 padded)
        v4i acc0[2][2], acc1[2][2], acc2[2][2], acc3[2][2], acc4[2][2];
        #pragma unroll
        for (int ta = 0; ta < 2; ++ta)
            #pragma unroll
            for (int oc = 0; oc < 2; ++oc) {
                acc0[ta][oc] = (v4i){0,0,0,0}; acc1[ta][oc] = (v4i){0,0,0,0};
                acc2[ta][oc] = (v4i){0,0,0,0}; acc3[ta][oc] = (v4i){0,0,0,0};
                acc4[ta][oc] = (v4i){0,0,0,0};
            }

        const int tbase = tc * 64 + wt * 32;     // wave's t-origin in XT

        // ---- K loop: no LDS, no barriers; fragments direct from L2 ----
        for (int kw = 0; kw < 8; ++kw) {         // 8 windows x 64 k
            const size_t kb0 = (size_t)(kw * 4 + lg) * KB_STRIDE;
            v4i aF[2][4], bF[2][4];
            #pragma unroll
            for (int p = 0; p < 4; ++p) {
                const size_t pp = (size_t)p * P_STRIDE + kb0;
                #pragma unroll
                for (int ta = 0; ta < 2; ++ta)
                    aF[ta][p] = *(const v4i*)(xb + pp
                                 + (size_t)(tbase + ta * 16 + lr) * 16);
                #pragma unroll
                for (int oc = 0; oc < 2; ++oc)
                    bF[oc][p] = *(const v4i*)(wb + pp
                                 + (size_t)(wo * 32 + oc * 16 + lr) * 16);
            }
            #pragma unroll
            for (int ta = 0; ta < 2; ++ta)
                #pragma unroll
                for (int oc = 0; oc < 2; ++oc) {
                    acc0[ta][oc] = MFMA_I8(aF[ta][0], bF[oc][2], acc0[ta][oc]);
                    acc0[ta][oc] = MFMA_I8(aF[ta][1], bF[oc][1], acc0[ta][oc]);
                    acc0[ta][oc] = MFMA_I8(aF[ta][2], bF[oc][0], acc0[ta][oc]);
                    acc1[ta][oc] = MFMA_I8(aF[ta][0], bF[oc][3], acc1[ta][oc]);
                    acc1[ta][oc] = MFMA_I8(aF[ta][1], bF[oc][2], acc1[ta][oc]);
                    acc1[ta][oc] = MFMA_I8(aF[ta][2], bF[oc][1], acc1[ta][oc]);
                    acc1[ta][oc] = MFMA_I8(aF[ta][3], bF[oc][0], acc1[ta][oc]);
                    acc2[ta][oc] = MFMA_I8(aF[ta][1], bF[oc][3], acc2[ta][oc]);
                    acc2[ta][oc] = MFMA_I8(aF[ta][2], bF[oc][2], acc2[ta][oc]);
                    acc2[ta][oc] = MFMA_I8(aF[ta][3], bF[oc][1], acc2[ta][oc]);
                    acc3[ta][oc] = MFMA_I8(aF[ta][2], bF[oc][3], acc3[ta][oc]);
                    acc3[ta][oc] = MFMA_I8(aF[ta][3], bF[oc][2], acc3[ta][oc]);
                    acc4[ta][oc] = MFMA_I8(aF[ta][3], bF[oc][3], acc4[ta][oc]);
                }
        }

        __syncthreads();   // previous chunk's scan reads complete
        // D: col = lane&15 (o), row = 4*(lane>>4)+reg (t) -- HW-verified r7.
        #pragma unroll
        for (int ta = 0; ta < 2; ++ta)
            #pragma unroll
            for (int oc = 0; oc < 2; ++oc) {
                const int o_loc = wo * 32 + oc * 16 + lr;
                #pragma unroll
                for (int r = 0; r < 4; ++r) {
                    const double iv =
                          (double)acc0[ta][oc][r] * 0x1p-27
                        + (double)acc1[ta][oc][r] * 0x1p-19
                        + (double)acc2[ta][oc][r] * 0x1p-11
                        + (double)acc3[ta][oc][r] * 0x1p-3
                        + (double)acc4[ta][oc][r] * 0x1p+5;
                    ib[wt * 32 + ta * 16 + lg * 4 + r][o_loc] = iv;
                }
            }
        __syncthreads();

        // ---- scan: each wave handles its 16 o-channels (lanes 0..15) ----
        if (lane < 16) {
            const int ol = wv * 16 + lane;               // local o 0..63
            float* py = yg + ((size_t)(b * NO) + o0 + ol) * NT + tc * 64;
            #pragma unroll
            for (int tb = 0; tb < 4; ++tb) {
                double iv[16];
                #pragma unroll
                for (int u = 0; u < 16; ++u) iv[u] = ib[tb * 16 + u][ol];
                float fv[16];
                #pragma unroll
                for (int u = 0; u < 16; ++u) {
                    v += (iv[u] - v) * alpha;
                    const bool s = (v >= 1.0);
                    fv[u] = s ? 1.0f : 0.0f;
                    if (s) v = 0.0;
                }
                const int tg = tc * 64 + tb * 16;
                #pragma unroll
                for (int q = 0; q < 4; ++q)
                    if (tg + q * 4 < NT)
                        *(float4*)(py + tb * 16 + q * 4) =
                            make_float4(fv[q*4], fv[q*4+1], fv[q*4+2], fv[q*4+3]);
            }
        }
    }
}

// ============ fallback: round-4 fused fp64 kernel (proven, ws-free) ============
#define OT 64
#define TT 64
#define KC 32
#define TP (TT + 2)
#define OP (OT + 2)

__global__ __launch_bounds__(256, 2)
void snn_v2(const float* __restrict__ xg, const float* __restrict__ wg,
            float* __restrict__ yg) {
    __shared__ double smem[KC * TP + KC * OP];
    double (*xs)[TP]  = (double(*)[TP])smem;
    double (*wsh)[OP] = (double(*)[OP])(smem + KC * TP);
    double (*ib)[OP]  = (double(*)[OP])smem;

    const int tid = threadIdx.x;
    const int p2  = (tid & 31) * 2;
    const int t0  = (tid >> 5) * 8;
    const int L   = blockIdx.x;
    const int b   = (L & 7) + ((L >> 6) << 3);
    const int o0  = ((L >> 3) & 7) * OT;
    const int sk  = tid >> 3;
    const int se  = (tid & 7) * 8;
    const double alpha = 0.001 / 50.0;
    double v = 0.0;

    for (int tc = 0; tc < NT; tc += TT) {
        const int tlim = (NT - tc < TT) ? (NT - tc) : TT;
        double a0[8], a1[8];
        #pragma unroll
        for (int j = 0; j < 8; ++j) { a0[j] = 0.0; a1[j] = 0.0; }

        for (int kc = 0; kc < NI; kc += KC) {
            __syncthreads();
            {
                const float* px = xg + ((size_t)(b * NI + kc + sk)) * NT + tc + se;
                double* dx = &xs[sk][se];
                if (tlim == TT) {
                    #pragma unroll
                    for (int e = 0; e < 2; ++e) {
                        float4 f = ((const float4*)px)[e];
                        d2 lo = {(double)f.x, (double)f.y};
                        d2 hi = {(double)f.z, (double)f.w};
                        *(d2*)(dx + e * 4) = lo; *(d2*)(dx + e * 4 + 2) = hi;
                    }
                } else {
                    #pragma unroll
                    for (int e = 0; e < 8; ++e) {
                        double val = 0.0;
                        if (se + e < tlim) val = (double)px[e];
                        dx[e] = val;
                    }
                }
            }
            {
                const float* pw = wg + (size_t)(kc + sk) * NO + o0 + se;
                double* dw = &wsh[sk][se];
                #pragma unroll
                for (int e = 0; e < 2; ++e) {
                    float4 f = ((const float4*)pw)[e];
                    d2 lo = {(double)f.x, (double)f.y};
                    d2 hi = {(double)f.z, (double)f.w};
                    *(d2*)(dw + e * 4) = lo; *(d2*)(dw + e * 4 + 2) = hi;
                }
            }
            __syncthreads();
            #pragma unroll 4
            for (int k = 0; k < KC; ++k) {
                const d2 w2 = *(const d2*)&wsh[k][p2];
                double x8[8];
                #pragma unroll
                for (int e = 0; e < 4; ++e)
                    *(d2*)&x8[e * 2] = *(const d2*)&xs[k][t0 + e * 2];
                #pragma unroll
                for (int j = 0; j < 8; ++j) {
                    a0[j] += x8[j] * w2[0];
                    a1[j] += x8[j] * w2[1];
                }
            }
        }
        __syncthreads();
        #pragma unroll
        for (int j = 0; j < 8; ++j) {
            d2 c = {a0[j], a1[j]};
            *(d2*)&ib[t0 + j][p2] = c;
        }
        __syncthreads();
        if (tid < 64) {
            float* py = yg + ((size_t)(b * NO + o0 + tid)) * NT + tc;
            for (int tb = 0; tb < TT; tb += 16) {
                double iv[16];
                #pragma unroll
                for (int u = 0; u < 16; ++u) iv[u] = ib[tb + u][tid];
                float fv[16];
                #pragma unroll
                for (int u = 0; u < 16; ++u) {
                    v += (iv[u] - v) * alpha;
                    const bool s = (v >= 1.0);
                    fv[u] = s ? 1.0f : 0.0f;
                    if (s) v = 0.0;
                }
                #pragma unroll
                for (int q = 0; q < 4; ++q)
                    if (tb + q * 4 < tlim)
                        *(float4*)(py + tb + q * 4) =
                            make_float4(fv[q*4], fv[q*4+1], fv[q*4+2], fv[q*4+3]);
            }
        }
    }
}

extern "C" void kernel_launch(void* const* d_in, const int* in_sizes, int n_in,
                              void* d_out, int out_size, void* d_ws, size_t ws_size,
                              hipStream_t stream) {
    const float* x = (const float*)d_in[0];   // [64, 512, 500]
    const float* w = (const float*)d_in[1];   // [512, 512]
    float* y = (float*)d_out;                 // [64, 512, 500]
    (void)in_sizes; (void)n_in; (void)out_size;

    const size_t need = (size_t)XT_BYTES + WT_BYTES;   // 68,157,440 B
    if (ws_size >= need) {
        unsigned char* xt  = (unsigned char*)d_ws;
        unsigned char* wtb = (unsigned char*)d_ws + XT_BYTES;
        prep_x<<<512, 256, 0, stream>>>(x, xt);
        prep_w<<<8, 256, 0, stream>>>(w, wtb);
        snn_i8v2<<<512, 256, 0, stream>>>(xt, wtb, y);
    } else {
        snn_v2<<<512, 256, 0, stream>>>(x, w, y);      // proven fallback
    }
}

// Round 9
// 257.851 us; speedup vs baseline: 2.0516x; 1.0401x over previous
//
#include <hip/hip_runtime.h>

// SNN layer on MI355X. i[t,b,o] = sum_k x[b,k,t]*w[k,o]; per-(b,o) sequential
// LIF scan over t; spikes (0/1) fp32 [B,O,T].
//
// Exact fixed-point i8-MFMA path (rounds 7-8 proven, absmax 0.0):
// X=rint(x*2^28) -> 4 signed i8 limbs, W=rint(w*2^15) -> 4 limbs; 13 limb
// pairs (p+q>=2) accumulated exactly in i32 (mfma_i32_16x16x64_i8), combined
// in fp64; eps_i ~ 3e-4 vs ~2e-3 budget.
//
// Round-8 post-mortem: register-direct K-loop was memory-LATENCY-bound
// (MfmaUtil 19%, VALUBusy 12%, both pipes idle; MFMA-busy ~= 57us floor).
// Each kw iteration stalled on vmcnt for its own 16 fresh L2 loads.
// This version: register PING-PONG double buffer -- issue kw+1's 16 loads
// before kw's 52 MFMAs (fully unrolled, static indices), so ~1060 cy of
// MFMA covers the ~600 cy load latency. prep_w merged into prep_x launch.

#define NB 64
#define NI 512
#define NO 512
#define NT 500

typedef int v4i __attribute__((ext_vector_type(4)));
typedef double d2 __attribute__((ext_vector_type(2)));

#define XT_B_STRIDE 1048576   // bytes per batch in XT
#define P_STRIDE    262144    // bytes per limb plane
#define KB_STRIDE   8192      // bytes per k-block (512 rows * 16B)
#define XT_BYTES    67108864
#define WT_BYTES    1048576

// ============ prep: x transpose+limb-slice (blocks 0..511), w (512..519) ====
__global__ __launch_bounds__(256)
void prep_xw(const float* __restrict__ xg, const float* __restrict__ wg,
             unsigned char* __restrict__ xt, unsigned char* __restrict__ wtb) {
    __shared__ float xs[64][65];
    const int tid = threadIdx.x;
    const int sk  = tid >> 2;
    const int st  = (tid & 3) * 16;
    const int ct  = tid & 63;
    const int ckb = tid >> 6;

    if (blockIdx.x < 512) {
        const int b  = blockIdx.x >> 3;
        const int kc = (blockIdx.x & 7) * 64;
        for (int tc = 0; tc < 512; tc += 64) {
            __syncthreads();
            const float* px = xg + ((size_t)(b * NI + kc + sk)) * NT + tc + st;
            #pragma unroll
            for (int e = 0; e < 16; ++e)
                xs[sk][st + e] = (tc + st + e < NT) ? px[e] : 0.0f;
            __syncthreads();

            unsigned int u0[4] = {0,0,0,0}, u1[4] = {0,0,0,0};
            unsigned int u2[4] = {0,0,0,0}, u3[4] = {0,0,0,0};
            #pragma unroll
            for (int e = 0; e < 16; ++e) {
                const float xv = xs[ckb * 16 + e][ct];
                int X = __float2int_rn(xv * 268435456.0f);    // x * 2^28
                const int a0 = (X << 24) >> 24; X = (X - a0) >> 8;
                const int a1 = (X << 24) >> 24; X = (X - a1) >> 8;
                const int a2 = (X << 24) >> 24; const int a3 = (X - a2) >> 8;
                const int sh = (e & 3) * 8; const int d = e >> 2;
                u0[d] |= (unsigned)(a0 & 0xFF) << sh;
                u1[d] |= (unsigned)(a1 & 0xFF) << sh;
                u2[d] |= (unsigned)(a2 & 0xFF) << sh;
                u3[d] |= (unsigned)(a3 & 0xFF) << sh;
            }
            unsigned char* base = xt + (size_t)b * XT_B_STRIDE
                                  + (size_t)(kc / 16 + ckb) * KB_STRIDE
                                  + (size_t)(tc + ct) * 16;
            *(uint4*)(base)                = make_uint4(u0[0], u0[1], u0[2], u0[3]);
            *(uint4*)(base + P_STRIDE)     = make_uint4(u1[0], u1[1], u1[2], u1[3]);
            *(uint4*)(base + 2 * P_STRIDE) = make_uint4(u2[0], u2[1], u2[2], u2[3]);
            *(uint4*)(base + 3 * P_STRIDE) = make_uint4(u3[0], u3[1], u3[2], u3[3]);
        }
    } else {
        const int kc = (blockIdx.x - 512) * 64;
        for (int oc = 0; oc < 512; oc += 64) {
            __syncthreads();
            const float* pw = wg + (size_t)(kc + sk) * NO + oc + st;
            #pragma unroll
            for (int e = 0; e < 16; e += 4) {
                float4 f = *(const float4*)(pw + e);
                xs[sk][st + e + 0] = f.x; xs[sk][st + e + 1] = f.y;
                xs[sk][st + e + 2] = f.z; xs[sk][st + e + 3] = f.w;
            }
            __syncthreads();

            unsigned int u0[4] = {0,0,0,0}, u1[4] = {0,0,0,0};
            unsigned int u2[4] = {0,0,0,0}, u3[4] = {0,0,0,0};
            #pragma unroll
            for (int e = 0; e < 16; ++e) {
                const float wv = xs[ckb * 16 + e][ct];
                int X = __float2int_rn(wv * 32768.0f);        // w * 2^15
                const int a0 = (X << 24) >> 24; X = (X - a0) >> 8;
                const int a1 = (X << 24) >> 24; X = (X - a1) >> 8;
                const int a2 = (X << 24) >> 24; const int a3 = (X - a2) >> 8;
                const int sh = (e & 3) * 8; const int d = e >> 2;
                u0[d] |= (unsigned)(a0 & 0xFF) << sh;
                u1[d] |= (unsigned)(a1 & 0xFF) << sh;
                u2[d] |= (unsigned)(a2 & 0xFF) << sh;
                u3[d] |= (unsigned)(a3 & 0xFF) << sh;
            }
            unsigned char* base = wtb + (size_t)(kc / 16 + ckb) * KB_STRIDE
                                  + (size_t)(oc + ct) * 16;
            *(uint4*)(base)                = make_uint4(u0[0], u0[1], u0[2], u0[3]);
            *(uint4*)(base + P_STRIDE)     = make_uint4(u1[0], u1[1], u1[2], u1[3]);
            *(uint4*)(base + 2 * P_STRIDE) = make_uint4(u2[0], u2[1], u2[2], u2[3]);
            *(uint4*)(base + 3 * P_STRIDE) = make_uint4(u3[0], u3[1], u3[2], u3[3]);
        }
    }
}

// ====== main: register-direct i8-MFMA GEMM (ping-pong prefetch) + scan ======
#define MFMA_I8(a, b, c) __builtin_amdgcn_mfma_i32_16x16x64_i8(a, b, c, 0, 0, 0)

__global__ __launch_bounds__(256, 2)
void snn_i8v3(const unsigned char* __restrict__ xt,
              const unsigned char* __restrict__ wtb,
              float* __restrict__ yg) {
    __shared__ double ib[64][66];        // 33,792 B (i-values only)

    const int tid  = threadIdx.x;
    const int lane = tid & 63;
    const int wv   = tid >> 6;      // wave 0..3
    const int wt   = wv & 1;        // t-half (32 rows)
    const int wo   = wv >> 1;       // o-half (32 cols)
    const int lr   = lane & 15;
    const int lg   = lane >> 4;

    // XCD swizzle (proven): 8 o-tiles of one batch share an XCD.
    const int L  = blockIdx.x;
    const int b  = (L & 7) + ((L >> 6) << 3);
    const int o0 = ((L >> 3) & 7) * 64;

    const unsigned char* xb = xt + (size_t)b * XT_B_STRIDE;
    const unsigned char* wb = wtb + (size_t)o0 * 16;

    const double alpha = 0.001 / 50.0;
    double v = 0.0;                 // scan state (lanes<16 of each wave)

    for (int tc = 0; tc < 8; ++tc) {            // 8 chunks of 64 t (512 padded)
        v4i acc0[2][2], acc1[2][2], acc2[2][2], acc3[2][2], acc4[2][2];
        #pragma unroll
        for (int ta = 0; ta < 2; ++ta)
            #pragma unroll
            for (int oc = 0; oc < 2; ++oc) {
                acc0[ta][oc] = (v4i){0,0,0,0}; acc1[ta][oc] = (v4i){0,0,0,0};
                acc2[ta][oc] = (v4i){0,0,0,0}; acc3[ta][oc] = (v4i){0,0,0,0};
                acc4[ta][oc] = (v4i){0,0,0,0};
            }

        const int tbase = tc * 64 + wt * 32;     // wave's t-origin in XT

        // register ping-pong: load kw+1 BEFORE kw's MFMAs (all static idx)
        v4i aP[2][2][4], bP[2][2][4];
        {   // prologue: load kw=0 into buffer 0
            const size_t kb0 = (size_t)lg * KB_STRIDE;
            #pragma unroll
            for (int p = 0; p < 4; ++p) {
                const size_t pp = (size_t)p * P_STRIDE + kb0;
                #pragma unroll
                for (int ta = 0; ta < 2; ++ta)
                    aP[0][ta][p] = *(const v4i*)(xb + pp
                                    + (size_t)(tbase + ta * 16 + lr) * 16);
                #pragma unroll
                for (int oc = 0; oc < 2; ++oc)
                    bP[0][oc][p] = *(const v4i*)(wb + pp
                                    + (size_t)(wo * 32 + oc * 16 + lr) * 16);
            }
        }

        #pragma unroll
        for (int kw = 0; kw < 8; ++kw) {
            const int cur = kw & 1, nxt = cur ^ 1;
            if (kw < 7) {                        // issue next window's loads
                const size_t kb0 = (size_t)((kw + 1) * 4 + lg) * KB_STRIDE;
                #pragma unroll
                for (int p = 0; p < 4; ++p) {
                    const size_t pp = (size_t)p * P_STRIDE + kb0;
                    #pragma unroll
                    for (int ta = 0; ta < 2; ++ta)
                        aP[nxt][ta][p] = *(const v4i*)(xb + pp
                                          + (size_t)(tbase + ta * 16 + lr) * 16);
                    #pragma unroll
                    for (int oc = 0; oc < 2; ++oc)
                        bP[nxt][oc][p] = *(const v4i*)(wb + pp
                                          + (size_t)(wo * 32 + oc * 16 + lr) * 16);
                }
            }
            #pragma unroll
            for (int ta = 0; ta < 2; ++ta)
                #pragma unroll
                for (int oc = 0; oc < 2; ++oc) {
                    acc0[ta][oc] = MFMA_I8(aP[cur][ta][0], bP[cur][oc][2], acc0[ta][oc]);
                    acc0[ta][oc] = MFMA_I8(aP[cur][ta][1], bP[cur][oc][1], acc0[ta][oc]);
                    acc0[ta][oc] = MFMA_I8(aP[cur][ta][2], bP[cur][oc][0], acc0[ta][oc]);
                    acc1[ta][oc] = MFMA_I8(aP[cur][ta][0], bP[cur][oc][3], acc1[ta][oc]);
                    acc1[ta][oc] = MFMA_I8(aP[cur][ta][1], bP[cur][oc][2], acc1[ta][oc]);
                    acc1[ta][oc] = MFMA_I8(aP[cur][ta][2], bP[cur][oc][1], acc1[ta][oc]);
                    acc1[ta][oc] = MFMA_I8(aP[cur][ta][3], bP[cur][oc][0], acc1[ta][oc]);
                    acc2[ta][oc] = MFMA_I8(aP[cur][ta][1], bP[cur][oc][3], acc2[ta][oc]);
                    acc2[ta][oc] = MFMA_I8(aP[cur][ta][2], bP[cur][oc][2], acc2[ta][oc]);
                    acc2[ta][oc] = MFMA_I8(aP[cur][ta][3], bP[cur][oc][1], acc2[ta][oc]);
                    acc3[ta][oc] = MFMA_I8(aP[cur][ta][2], bP[cur][oc][3], acc3[ta][oc]);
                    acc3[ta][oc] = MFMA_I8(aP[cur][ta][3], bP[cur][oc][2], acc3[ta][oc]);
                    acc4[ta][oc] = MFMA_I8(aP[cur][ta][3], bP[cur][oc][3], acc4[ta][oc]);
                }
        }

        __syncthreads();   // previous chunk's scan reads complete
        // D: col = lane&15 (o), row = 4*(lane>>4)+reg (t) -- HW-verified r7/r8.
        #pragma unroll
        for (int ta = 0; ta < 2; ++ta)
            #pragma unroll
            for (int oc = 0; oc < 2; ++oc) {
                const int o_loc = wo * 32 + oc * 16 + lr;
                #pragma unroll
                for (int r = 0; r < 4; ++r) {
                    const double iv =
                          (double)acc0[ta][oc][r] * 0x1p-27
                        + (double)acc1[ta][oc][r] * 0x1p-19
                        + (double)acc2[ta][oc][r] * 0x1p-11
                        + (double)acc3[ta][oc][r] * 0x1p-3
                        + (double)acc4[ta][oc][r] * 0x1p+5;
                    ib[wt * 32 + ta * 16 + lg * 4 + r][o_loc] = iv;
                }
            }
        __syncthreads();

        // ---- scan: each wave handles its 16 o-channels (lanes 0..15) ----
        if (lane < 16) {
            const int ol = wv * 16 + lane;               // local o 0..63
            float* py = yg + ((size_t)(b * NO) + o0 + ol) * NT + tc * 64;
            #pragma unroll
            for (int tb = 0; tb < 4; ++tb) {
                double iv[16];
                #pragma unroll
                for (int u = 0; u < 16; ++u) iv[u] = ib[tb * 16 + u][ol];
                float fv[16];
                #pragma unroll
                for (int u = 0; u < 16; ++u) {
                    v += (iv[u] - v) * alpha;
                    const bool s = (v >= 1.0);
                    fv[u] = s ? 1.0f : 0.0f;
                    if (s) v = 0.0;
                }
                const int tg = tc * 64 + tb * 16;
                #pragma unroll
                for (int q = 0; q < 4; ++q)
                    if (tg + q * 4 < NT)
                        *(float4*)(py + tb * 16 + q * 4) =
                            make_float4(fv[q*4], fv[q*4+1], fv[q*4+2], fv[q*4+3]);
            }
        }
    }
}

// ============ fallback: round-4 fused fp64 kernel (proven, ws-free) ============
#define OT 64
#define TT 64
#define KC 32
#define TP (TT + 2)
#define OP (OT + 2)

__global__ __launch_bounds__(256, 2)
void snn_v2(const float* __restrict__ xg, const float* __restrict__ wg,
            float* __restrict__ yg) {
    __shared__ double smem[KC * TP + KC * OP];
    double (*xs)[TP]  = (double(*)[TP])smem;
    double (*wsh)[OP] = (double(*)[OP])(smem + KC * TP);
    double (*ib)[OP]  = (double(*)[OP])smem;

    const int tid = threadIdx.x;
    const int p2  = (tid & 31) * 2;
    const int t0  = (tid >> 5) * 8;
    const int L   = blockIdx.x;
    const int b   = (L & 7) + ((L >> 6) << 3);
    const int o0  = ((L >> 3) & 7) * OT;
    const int sk  = tid >> 3;
    const int se  = (tid & 7) * 8;
    const double alpha = 0.001 / 50.0;
    double v = 0.0;

    for (int tc = 0; tc < NT; tc += TT) {
        const int tlim = (NT - tc < TT) ? (NT - tc) : TT;
        double a0[8], a1[8];
        #pragma unroll
        for (int j = 0; j < 8; ++j) { a0[j] = 0.0; a1[j] = 0.0; }

        for (int kc = 0; kc < NI; kc += KC) {
            __syncthreads();
            {
                const float* px = xg + ((size_t)(b * NI + kc + sk)) * NT + tc + se;
                double* dx = &xs[sk][se];
                if (tlim == TT) {
                    #pragma unroll
                    for (int e = 0; e < 2; ++e) {
                        float4 f = ((const float4*)px)[e];
                        d2 lo = {(double)f.x, (double)f.y};
                        d2 hi = {(double)f.z, (double)f.w};
                        *(d2*)(dx + e * 4) = lo; *(d2*)(dx + e * 4 + 2) = hi;
                    }
                } else {
                    #pragma unroll
                    for (int e = 0; e < 8; ++e) {
                        double val = 0.0;
                        if (se + e < tlim) val = (double)px[e];
                        dx[e] = val;
                    }
                }
            }
            {
                const float* pw = wg + (size_t)(kc + sk) * NO + o0 + se;
                double* dw = &wsh[sk][se];
                #pragma unroll
                for (int e = 0; e < 2; ++e) {
                    float4 f = ((const float4*)pw)[e];
                    d2 lo = {(double)f.x, (double)f.y};
                    d2 hi = {(double)f.z, (double)f.w};
                    *(d2*)(dw + e * 4) = lo; *(d2*)(dw + e * 4 + 2) = hi;
                }
            }
            __syncthreads();
            #pragma unroll 4
            for (int k = 0; k < KC; ++k) {
                const d2 w2 = *(const d2*)&wsh[k][p2];
                double x8[8];
                #pragma unroll
                for (int e = 0; e < 4; ++e)
                    *(d2*)&x8[e * 2] = *(const d2*)&xs[k][t0 + e * 2];
                #pragma unroll
                for (int j = 0; j < 8; ++j) {
                    a0[j] += x8[j] * w2[0];
                    a1[j] += x8[j] * w2[1];
                }
            }
        }
        __syncthreads();
        #pragma unroll
        for (int j = 0; j < 8; ++j) {
            d2 c = {a0[j], a1[j]};
            *(d2*)&ib[t0 + j][p2] = c;
        }
        __syncthreads();
        if (tid < 64) {
            float* py = yg + ((size_t)(b * NO + o0 + tid)) * NT + tc;
            for (int tb = 0; tb < TT; tb += 16) {
                double iv[16];
                #pragma unroll
                for (int u = 0; u < 16; ++u) iv[u] = ib[tb + u][tid];
                float fv[16];
                #pragma unroll
                for (int u = 0; u < 16; ++u) {
                    v += (iv[u] - v) * alpha;
                    const bool s = (v >= 1.0);
                    fv[u] = s ? 1.0f : 0.0f;
                    if (s) v = 0.0;
                }
                #pragma unroll
                for (int q = 0; q < 4; ++q)
                    if (tb + q * 4 < tlim)
                        *(float4*)(py + tb + q * 4) =
                            make_float4(fv[q*4], fv[q*4+1], fv[q*4+2], fv[q*4+3]);
            }
        }
    }
}

extern "C" void kernel_launch(void* const* d_in, const int* in_sizes, int n_in,
                              void* d_out, int out_size, void* d_ws, size_t ws_size,
                              hipStream_t stream) {
    const float* x = (const float*)d_in[0];   // [64, 512, 500]
    const float* w = (const float*)d_in[1];   // [512, 512]
    float* y = (float*)d_out;                 // [64, 512, 500]
    (void)in_sizes; (void)n_in; (void)out_size;

    const size_t need = (size_t)XT_BYTES + WT_BYTES;   // 68,157,440 B
    if (ws_size >= need) {
        unsigned char* xt  = (unsigned char*)d_ws;
        unsigned char* wtb = (unsigned char*)d_ws + XT_BYTES;
        prep_xw<<<520, 256, 0, stream>>>(x, w, xt, wtb);
        snn_i8v3<<<512, 256, 0, stream>>>(xt, wtb, y);
    } else {
        snn_v2<<<512, 256, 0, stream>>>(x, w, y);      // proven fallback
    }
}